// Round 2
// baseline (209.072 us; speedup 1.0000x reference)
//
#include <hip/hip_runtime.h>

// src (B,C,D,H,W) f32, flow (B,3,D,H,W) f32, C==1
constexpr int B  = 2;
constexpr int D  = 160;
constexpr int H  = 192;
constexpr int W  = 224;
constexpr int HW = H * W;        // 43008
constexpr int N  = D * HW;       // 6,881,280 per volume
constexpr int TOTAL = B * N;     // 13,762,560
constexpr int VPT = 4;           // voxels (x-consecutive) per thread; W%4==0
constexpr int NTHREADS = TOTAL / VPT;

__global__ __launch_bounds__(256) void st3d_warp_v2(
    const float* __restrict__ src,
    const float* __restrict__ flow,
    float* __restrict__ out)
{
    int tid = blockIdx.x * blockDim.x + threadIdx.x;
    if (tid >= NTHREADS) return;

    int n4 = tid * VPT;              // flat voxel index of first element
    int b  = n4 / N;
    int n  = n4 - b * N;
    int z  = n / HW;
    int r  = n - z * HW;
    int y  = r / W;
    int x  = r - y * W;              // multiple of 4, 4 voxels stay in-row

    const float* fl = flow + (size_t)b * 3 * N;
    float4 dz4 = *reinterpret_cast<const float4*>(fl + n);
    float4 dy4 = *reinterpret_cast<const float4*>(fl + N + n);
    float4 dx4 = *reinterpret_cast<const float4*>(fl + 2 * N + n);
    const float* dzp = reinterpret_cast<const float*>(&dz4);
    const float* dyp = reinterpret_cast<const float*>(&dy4);
    const float* dxp = reinterpret_cast<const float*>(&dx4);

    const float* s = src + (size_t)b * N;   // C == 1

    float res[VPT];
#pragma unroll
    for (int j = 0; j < VPT; ++j) {
        float cz = (float)z       + dzp[j];
        float cy = (float)y       + dyp[j];
        float cx = (float)(x + j) + dxp[j];

        float fz0 = floorf(cz); int z0 = (int)fz0; float fz = cz - fz0;
        float fy0 = floorf(cy); int y0 = (int)fy0; float fy = cy - fy0;
        float fx0 = floorf(cx); int x0 = (int)fx0; float fx = cx - fx0;
        int z1 = z0 + 1, y1 = y0 + 1, x1 = x0 + 1;

        // per-axis weights with validity folded in (corner valid factors
        // as vz*vy*vx — identical to reference semantics)
        float wz0 = (1.0f - fz) * ((z0 >= 0 && z0 < D) ? 1.0f : 0.0f);
        float wz1 = fz          * ((z1 >= 0 && z1 < D) ? 1.0f : 0.0f);
        float wy0 = (1.0f - fy) * ((y0 >= 0 && y0 < H) ? 1.0f : 0.0f);
        float wy1 = fy          * ((y1 >= 0 && y1 < H) ? 1.0f : 0.0f);
        float wx0 = (1.0f - fx) * ((x0 >= 0 && x0 < W) ? 1.0f : 0.0f);
        float wx1 = fx          * ((x1 >= 0 && x1 < W) ? 1.0f : 0.0f);

        int zc0 = min(max(z0, 0), D - 1), zc1 = min(max(z1, 0), D - 1);
        int yc0 = min(max(y0, 0), H - 1), yc1 = min(max(y1, 0), H - 1);
        int xc0 = min(max(x0, 0), W - 1), xc1 = min(max(x1, 0), W - 1);

        const float* sz0 = s + zc0 * HW;
        const float* sz1 = s + zc1 * HW;
        int ry0 = yc0 * W, ry1 = yc1 * W;

        float v000 = sz0[ry0 + xc0], v001 = sz0[ry0 + xc1];
        float v010 = sz0[ry1 + xc0], v011 = sz0[ry1 + xc1];
        float v100 = sz1[ry0 + xc0], v101 = sz1[ry0 + xc1];
        float v110 = sz1[ry1 + xc0], v111 = sz1[ry1 + xc1];

        res[j] = v000 * (wz0 * wy0 * wx0) + v001 * (wz0 * wy0 * wx1)
               + v010 * (wz0 * wy1 * wx0) + v011 * (wz0 * wy1 * wx1)
               + v100 * (wz1 * wy0 * wx0) + v101 * (wz1 * wy0 * wx1)
               + v110 * (wz1 * wy1 * wx0) + v111 * (wz1 * wy1 * wx1);
    }

    *reinterpret_cast<float4*>(out + n4) =
        make_float4(res[0], res[1], res[2], res[3]);
}

extern "C" void kernel_launch(void* const* d_in, const int* in_sizes, int n_in,
                              void* d_out, int out_size, void* d_ws, size_t ws_size,
                              hipStream_t stream)
{
    const float* src  = (const float*)d_in[0];
    const float* flow = (const float*)d_in[1];
    float* out = (float*)d_out;

    int blocks = (NTHREADS + 255) / 256;
    st3d_warp_v2<<<blocks, 256, 0, stream>>>(src, flow, out);
}

// Round 3
// 130.939 us; speedup vs baseline: 1.5967x; 1.5967x over previous
//
#include <hip/hip_runtime.h>

// src (B,C,D,H,W) f32, flow (B,3,D,H,W) f32, C==1
constexpr int B  = 2;
constexpr int D  = 160;
constexpr int H  = 192;
constexpr int W  = 224;
constexpr int HW = H * W;        // 43008
constexpr int N  = D * HW;       // 6,881,280 per volume (divisible by 1024)
constexpr int TOTAL = B * N;     // 13,762,560
constexpr int BLK = 256;
constexpr int VPT = 4;           // voxels per thread, strided by BLK
constexpr int PER_BLOCK = BLK * VPT;              // 1024
constexpr int NBLOCKS = TOTAL / PER_BLOCK;        // 13440 exact

__global__ __launch_bounds__(BLK) void st3d_warp_v3(
    const float* __restrict__ src,
    const float* __restrict__ flow,
    float* __restrict__ out)
{
    const int base = blockIdx.x * PER_BLOCK + threadIdx.x;

    // ---- phase 1: load all flow components (12 independent loads) ----
    float dz_[VPT], dy_[VPT], dx_[VPT];
    int   bb_[VPT], zz_[VPT], yy_[VPT], xx_[VPT], nn_[VPT];
#pragma unroll
    for (int j = 0; j < VPT; ++j) {
        int gid = base + j * BLK;
        int b = gid / N;
        int n = gid - b * N;
        int z = n / HW;
        int r = n - z * HW;
        int y = r / W;
        int x = r - y * W;
        bb_[j] = b; zz_[j] = z; yy_[j] = y; xx_[j] = x; nn_[j] = n;
        const float* fl = flow + (size_t)b * 3 * N;
        dz_[j] = fl[n];
        dy_[j] = fl[N + n];
        dx_[j] = fl[2 * N + n];
    }

    // ---- phase 2: addresses + weights, issue all 32 gathers ----
    float w_[VPT][8];
    float v_[VPT][8];
#pragma unroll
    for (int j = 0; j < VPT; ++j) {
        float cz = (float)zz_[j] + dz_[j];
        float cy = (float)yy_[j] + dy_[j];
        float cx = (float)xx_[j] + dx_[j];

        float fz0 = floorf(cz); int z0 = (int)fz0; float fz = cz - fz0;
        float fy0 = floorf(cy); int y0 = (int)fy0; float fy = cy - fy0;
        float fx0 = floorf(cx); int x0 = (int)fx0; float fx = cx - fx0;
        int z1 = z0 + 1, y1 = y0 + 1, x1 = x0 + 1;

        float wz0 = (1.0f - fz) * ((z0 >= 0 && z0 < D) ? 1.0f : 0.0f);
        float wz1 = fz          * ((z1 >= 0 && z1 < D) ? 1.0f : 0.0f);
        float wy0 = (1.0f - fy) * ((y0 >= 0 && y0 < H) ? 1.0f : 0.0f);
        float wy1 = fy          * ((y1 >= 0 && y1 < H) ? 1.0f : 0.0f);
        float wx0 = (1.0f - fx) * ((x0 >= 0 && x0 < W) ? 1.0f : 0.0f);
        float wx1 = fx          * ((x1 >= 0 && x1 < W) ? 1.0f : 0.0f);

        w_[j][0] = wz0 * wy0 * wx0;  w_[j][1] = wz0 * wy0 * wx1;
        w_[j][2] = wz0 * wy1 * wx0;  w_[j][3] = wz0 * wy1 * wx1;
        w_[j][4] = wz1 * wy0 * wx0;  w_[j][5] = wz1 * wy0 * wx1;
        w_[j][6] = wz1 * wy1 * wx0;  w_[j][7] = wz1 * wy1 * wx1;

        int zc0 = min(max(z0, 0), D - 1), zc1 = min(max(z1, 0), D - 1);
        int yc0 = min(max(y0, 0), H - 1), yc1 = min(max(y1, 0), H - 1);
        int xc0 = min(max(x0, 0), W - 1), xc1 = min(max(x1, 0), W - 1);

        const float* s   = src + (size_t)bb_[j] * N;
        const float* sz0 = s + zc0 * HW;
        const float* sz1 = s + zc1 * HW;
        int ry0 = yc0 * W, ry1 = yc1 * W;

        v_[j][0] = sz0[ry0 + xc0];  v_[j][1] = sz0[ry0 + xc1];
        v_[j][2] = sz0[ry1 + xc0];  v_[j][3] = sz0[ry1 + xc1];
        v_[j][4] = sz1[ry0 + xc0];  v_[j][5] = sz1[ry0 + xc1];
        v_[j][6] = sz1[ry1 + xc0];  v_[j][7] = sz1[ry1 + xc1];
    }

    // ---- phase 3: weighted sums + coalesced stores ----
#pragma unroll
    for (int j = 0; j < VPT; ++j) {
        float acc = v_[j][0] * w_[j][0] + v_[j][1] * w_[j][1]
                  + v_[j][2] * w_[j][2] + v_[j][3] * w_[j][3]
                  + v_[j][4] * w_[j][4] + v_[j][5] * w_[j][5]
                  + v_[j][6] * w_[j][6] + v_[j][7] * w_[j][7];
        out[base + j * BLK] = acc;
    }
}

extern "C" void kernel_launch(void* const* d_in, const int* in_sizes, int n_in,
                              void* d_out, int out_size, void* d_ws, size_t ws_size,
                              hipStream_t stream)
{
    const float* src  = (const float*)d_in[0];
    const float* flow = (const float*)d_in[1];
    float* out = (float*)d_out;

    st3d_warp_v3<<<NBLOCKS, BLK, 0, stream>>>(src, flow, out);
}

// Round 6
// 115.762 us; speedup vs baseline: 1.8061x; 1.1311x over previous
//
#include <hip/hip_runtime.h>

// src (B,C,D,H,W) f32, flow (B,3,D,H,W) f32, C==1
constexpr int B  = 2;
constexpr int D  = 160;
constexpr int H  = 192;
constexpr int W  = 224;
constexpr int HW = H * W;        // 43008
constexpr int N  = D * HW;       // 6,881,280 per volume
constexpr int TOTAL = B * N;     // 13,762,560  (divisible by 256)

typedef float f2 __attribute__((ext_vector_type(2)));
// 8-byte vector load with only 4-byte alignment guarantee (gfx950 supports
// unaligned global access; LLVM emits a single global_load_dwordx2)
struct __attribute__((packed, aligned(4))) f2u { f2 v; };

__global__ __launch_bounds__(256) void st3d_warp_v4(
    const float* __restrict__ src,
    const float* __restrict__ flow,
    float* __restrict__ out)
{
    int gid = blockIdx.x * 256 + threadIdx.x;   // TOTAL % 256 == 0, no guard

    int b = gid / N;
    int n = gid - b * N;
    int z = n / HW;
    int r = n - z * HW;
    int y = r / W;
    int x = r - y * W;

    const float* fl = flow + (size_t)b * 3 * N;
    float cz = (float)z + fl[n];
    float cy = (float)y + fl[N + n];
    float cx = (float)x + fl[2 * N + n];

    float fz0 = floorf(cz); int z0 = (int)fz0; float fz = cz - fz0;
    float fy0 = floorf(cy); int y0 = (int)fy0; float fy = cy - fy0;
    float fx0 = floorf(cx); int x0 = (int)fx0; float fx = cx - fx0;
    int z1 = z0 + 1, y1 = y0 + 1, x1 = x0 + 1;

    // x-pair base: one 8B load per (z,y) face covers both x-corners.
    // All "wrong-slot" cases carry weight 0 (validity masks), so the lane
    // selects below are exact vs the reference:
    //   x0 in [0,W-2]: xb=x0    -> vx0=p.x, vx1=p.y
    //   x0 == -1     : xb=0     -> vx0 dead, vx1=p.x
    //   x0 == W-1    : xb=W-2   -> vx0=p.y, vx1 dead
    //   else         : both dead
    int  xb   = min(max(x0, 0), W - 2);
    bool sel0 = (x0 == xb);
    bool sel1 = (x0 <  xb);

    int zc0 = min(max(z0, 0), D - 1), zc1 = min(max(z1, 0), D - 1);
    int yc0 = min(max(y0, 0), H - 1), yc1 = min(max(y1, 0), H - 1);

    const float* s = src + (size_t)b * N;   // C == 1
    const float* a00 = s + zc0 * HW + yc0 * W + xb;
    const float* a01 = s + zc0 * HW + yc1 * W + xb;
    const float* a10 = s + zc1 * HW + yc0 * W + xb;
    const float* a11 = s + zc1 * HW + yc1 * W + xb;

    // 4 independent 8B gathers (compiler batches, single vmcnt wait)
    f2 p00 = ((const f2u*)a00)->v;
    f2 p01 = ((const f2u*)a01)->v;
    f2 p10 = ((const f2u*)a10)->v;
    f2 p11 = ((const f2u*)a11)->v;

    float wz0 = (1.0f - fz) * ((z0 >= 0 && z0 < D) ? 1.0f : 0.0f);
    float wz1 = fz          * ((z1 >= 0 && z1 < D) ? 1.0f : 0.0f);
    float wy0 = (1.0f - fy) * ((y0 >= 0 && y0 < H) ? 1.0f : 0.0f);
    float wy1 = fy          * ((y1 >= 0 && y1 < H) ? 1.0f : 0.0f);
    float wx0 = (1.0f - fx) * ((x0 >= 0 && x0 < W) ? 1.0f : 0.0f);
    float wx1 = fx          * ((x1 >= 0 && x1 < W) ? 1.0f : 0.0f);

    // per-face x-interp with lane selects
    float f00 = (sel0 ? p00.x : p00.y) * wx0 + (sel1 ? p00.x : p00.y) * wx1;
    float f01 = (sel0 ? p01.x : p01.y) * wx0 + (sel1 ? p01.x : p01.y) * wx1;
    float f10 = (sel0 ? p10.x : p10.y) * wx0 + (sel1 ? p10.x : p10.y) * wx1;
    float f11 = (sel0 ? p11.x : p11.y) * wx0 + (sel1 ? p11.x : p11.y) * wx1;

    float acc = wz0 * (wy0 * f00 + wy1 * f01)
              + wz1 * (wy0 * f10 + wy1 * f11);

    out[gid] = acc;
}

extern "C" void kernel_launch(void* const* d_in, const int* in_sizes, int n_in,
                              void* d_out, int out_size, void* d_ws, size_t ws_size,
                              hipStream_t stream)
{
    const float* src  = (const float*)d_in[0];
    const float* flow = (const float*)d_in[1];
    float* out = (float*)d_out;

    st3d_warp_v4<<<TOTAL / 256, 256, 0, stream>>>(src, flow, out);
}

// Round 7
// 91.049 us; speedup vs baseline: 2.2963x; 1.2714x over previous
//
#include <hip/hip_runtime.h>

// src (B,C,D,H,W) f32, flow (B,3,D,H,W) f32, C==1
constexpr int B  = 2;
constexpr int D  = 160;
constexpr int H  = 192;
constexpr int W  = 224;
constexpr int HW = H * W;        // 43008
constexpr int N  = D * HW;       // 6,881,280 per volume
// Block tile: 32x * 4y * 2z = 256 voxels, 1 per thread.
// Grid: (W/32) * (H/4) * (D/2) * B = 7 * 48 * 80 * 2 = 53760 blocks
constexpr int GX = W / 32;       // 7
constexpr int GY = H / 4;        // 48
constexpr int GZ = D / 2;        // 80
constexpr int NBLOCKS = GX * GY * GZ * B;

typedef float f2 __attribute__((ext_vector_type(2)));
// 8-byte vector load with only 4-byte alignment guarantee
struct __attribute__((packed, aligned(4))) f2u { f2 v; };

__global__ __launch_bounds__(256) void st3d_warp_v5(
    const float* __restrict__ src,
    const float* __restrict__ flow,
    float* __restrict__ out)
{
    // block -> 3D tile origin
    int tmp = blockIdx.x;
    int bx = tmp % GX; tmp /= GX;
    int by = tmp % GY; tmp /= GY;
    int bz = tmp % GZ;
    int b  = tmp / GZ;

    // thread -> voxel within tile (lanes: 32 x-consecutive x 2 y-rows)
    int tid = threadIdx.x;
    int dx = tid & 31;
    int dy = (tid >> 5) & 3;
    int dz = tid >> 7;

    int x = bx * 32 + dx;
    int y = by * 4  + dy;
    int z = bz * 2  + dz;
    int n = z * HW + y * W + x;

    const float* fl = flow + (size_t)b * 3 * N;
    float cz = (float)z + fl[n];
    float cy = (float)y + fl[N + n];
    float cx = (float)x + fl[2 * N + n];

    float fz0 = floorf(cz); int z0 = (int)fz0; float fz = cz - fz0;
    float fy0 = floorf(cy); int y0 = (int)fy0; float fy = cy - fy0;
    float fx0 = floorf(cx); int x0 = (int)fx0; float fx = cx - fx0;
    int z1 = z0 + 1, y1 = y0 + 1, x1 = x0 + 1;

    // x-pair base: one 8B load per (z,y) face covers both x-corners.
    //   x0 in [0,W-2]: xb=x0    -> vx0=p.x, vx1=p.y
    //   x0 == -1     : xb=0     -> vx0 dead, vx1=p.x
    //   x0 == W-1    : xb=W-2   -> vx0=p.y, vx1 dead
    //   else         : both dead (weights 0)
    int  xb   = min(max(x0, 0), W - 2);
    bool sel0 = (x0 == xb);
    bool sel1 = (x0 <  xb);

    int zc0 = min(max(z0, 0), D - 1), zc1 = min(max(z1, 0), D - 1);
    int yc0 = min(max(y0, 0), H - 1), yc1 = min(max(y1, 0), H - 1);

    const float* s = src + (size_t)b * N;   // C == 1
    const float* a00 = s + zc0 * HW + yc0 * W + xb;
    const float* a01 = s + zc0 * HW + yc1 * W + xb;
    const float* a10 = s + zc1 * HW + yc0 * W + xb;
    const float* a11 = s + zc1 * HW + yc1 * W + xb;

    f2 p00 = ((const f2u*)a00)->v;
    f2 p01 = ((const f2u*)a01)->v;
    f2 p10 = ((const f2u*)a10)->v;
    f2 p11 = ((const f2u*)a11)->v;

    float wz0 = (1.0f - fz) * ((z0 >= 0 && z0 < D) ? 1.0f : 0.0f);
    float wz1 = fz          * ((z1 >= 0 && z1 < D) ? 1.0f : 0.0f);
    float wy0 = (1.0f - fy) * ((y0 >= 0 && y0 < H) ? 1.0f : 0.0f);
    float wy1 = fy          * ((y1 >= 0 && y1 < H) ? 1.0f : 0.0f);
    float wx0 = (1.0f - fx) * ((x0 >= 0 && x0 < W) ? 1.0f : 0.0f);
    float wx1 = fx          * ((x1 >= 0 && x1 < W) ? 1.0f : 0.0f);

    float f00 = (sel0 ? p00.x : p00.y) * wx0 + (sel1 ? p00.x : p00.y) * wx1;
    float f01 = (sel0 ? p01.x : p01.y) * wx0 + (sel1 ? p01.x : p01.y) * wx1;
    float f10 = (sel0 ? p10.x : p10.y) * wx0 + (sel1 ? p10.x : p10.y) * wx1;
    float f11 = (sel0 ? p11.x : p11.y) * wx0 + (sel1 ? p11.x : p11.y) * wx1;

    float acc = wz0 * (wy0 * f00 + wy1 * f01)
              + wz1 * (wy0 * f10 + wy1 * f11);

    out[(size_t)b * N + n] = acc;
}

extern "C" void kernel_launch(void* const* d_in, const int* in_sizes, int n_in,
                              void* d_out, int out_size, void* d_ws, size_t ws_size,
                              hipStream_t stream)
{
    const float* src  = (const float*)d_in[0];
    const float* flow = (const float*)d_in[1];
    float* out = (float*)d_out;

    st3d_warp_v5<<<NBLOCKS, 256, 0, stream>>>(src, flow, out);
}